// Round 2
// baseline (165.564 us; speedup 1.0000x reference)
//
#include <hip/hip_runtime.h>

// DeepClusterLoss: out[0]=total, out[1]=recon_loss, out[2]=cluster_loss
// recon_loss = sum((recon_x - x)^2)   over [N=1e6, D=64] f32
// cluster_loss = sum((x - centers[assign])^2)
// ALPHA = BETA = 1.0

#define NROWS 1000000
#define DCOLS 64
#define KCLUST 100
#define BLOCK 256
#define GRID 3125   // 62500 row-groups / 3125 = 20 per block = 10 unrolled pairs, exact

__global__ void dcl_zero_out(float* __restrict__ out) {
    out[0] = 0.0f;
    out[1] = 0.0f;
    out[2] = 0.0f;
}

__device__ __forceinline__ void accum_group(
    int g, int r, int col,
    const float* __restrict__ recon_x,
    const float* __restrict__ x,
    const int* __restrict__ assign,
    const float* __restrict__ centers,
    float& racc, float& cacc)
{
    const int row = g * 16 + r;
    const int c = assign[row];
    const long long base = (long long)row * DCOLS + col;

    const float4 xv = *reinterpret_cast<const float4*>(x + base);
    const float4 rv = *reinterpret_cast<const float4*>(recon_x + base);
    const float4 cv = *reinterpret_cast<const float4*>(centers + c * DCOLS + col);

    float d0 = rv.x - xv.x;
    float d1 = rv.y - xv.y;
    float d2 = rv.z - xv.z;
    float d3 = rv.w - xv.w;
    racc += d0 * d0 + d1 * d1 + d2 * d2 + d3 * d3;

    float e0 = xv.x - cv.x;
    float e1 = xv.y - cv.y;
    float e2 = xv.z - cv.z;
    float e3 = xv.w - cv.w;
    cacc += e0 * e0 + e1 * e1 + e2 * e2 + e3 * e3;
}

__global__ __launch_bounds__(BLOCK, 8) void dcl_main(
    const float* __restrict__ recon_x,
    const float* __restrict__ x,
    const int* __restrict__ assign,
    const float* __restrict__ centers,
    float* __restrict__ out)
{
    const int t   = threadIdx.x;
    const int r   = t >> 4;       // row within 16-row group: 0..15
    const int col = (t & 15) * 4; // float4 slot within row

    float racc = 0.0f;
    float cacc = 0.0f;

    const int total_groups = NROWS / 16;  // 62500
    // 2x unrolled grid-stride: GRID*2 stride, both halves always valid
    // (62500 = 20 * 3125, so g and g+GRID both < total when loop entered
    //  since stride 2*GRID and 20 is even).
    for (int g = blockIdx.x; g < total_groups; g += 2 * GRID) {
        accum_group(g,        r, col, recon_x, x, assign, centers, racc, cacc);
        accum_group(g + GRID, r, col, recon_x, x, assign, centers, racc, cacc);
    }

    // wave-64 butterfly reduce
    #pragma unroll
    for (int off = 32; off > 0; off >>= 1) {
        racc += __shfl_down(racc, off);
        cacc += __shfl_down(cacc, off);
    }

    __shared__ float wsum_r[BLOCK / 64];
    __shared__ float wsum_c[BLOCK / 64];
    const int wave = t >> 6;
    if ((t & 63) == 0) {
        wsum_r[wave] = racc;
        wsum_c[wave] = cacc;
    }
    __syncthreads();

    if (t == 0) {
        float R = 0.0f, C = 0.0f;
        #pragma unroll
        for (int w = 0; w < BLOCK / 64; ++w) { R += wsum_r[w]; C += wsum_c[w]; }
        atomicAdd(&out[1], R);
        atomicAdd(&out[2], C);
        atomicAdd(&out[0], R + C);   // ALPHA=BETA=1
    }
}

extern "C" void kernel_launch(void* const* d_in, const int* in_sizes, int n_in,
                              void* d_out, int out_size, void* d_ws, size_t ws_size,
                              hipStream_t stream) {
    const float* recon_x = (const float*)d_in[0];
    const float* x       = (const float*)d_in[1];
    const int*   assign  = (const int*)d_in[2];
    const float* centers = (const float*)d_in[3];
    float* out = (float*)d_out;

    dcl_zero_out<<<1, 1, 0, stream>>>(out);
    dcl_main<<<GRID, BLOCK, 0, stream>>>(recon_x, x, assign, centers, out);
}

// Round 3
// 158.070 us; speedup vs baseline: 1.0474x; 1.0474x over previous
//
#include <hip/hip_runtime.h>

// DeepClusterLoss: out[0]=total, out[1]=recon_loss, out[2]=cluster_loss
// recon_loss = sum((recon_x - x)^2)   over [N=1e6, D=64] f32
// cluster_loss = sum((x - centers[assign])^2)
// ALPHA = BETA = 1.0

#define NROWS  1000000
#define DCOLS  64
#define BLOCK  256
#define GRID   3125               // 62500 groups / 3125 = 20 per block = 5 chunks of 4, exact
#define CHUNK  (GRID * 1024)      // float stride per k-step (GRID groups * 16 rows * 64 cols)
#define ARSTEP (GRID * 16)        // assignment-row stride per k-step

__global__ void dcl_zero_out(float* __restrict__ out) {
    out[0] = 0.0f;
    out[1] = 0.0f;
    out[2] = 0.0f;
}

__device__ __forceinline__ float sq4(float4 a, float4 b) {
    float d0 = a.x - b.x, d1 = a.y - b.y, d2 = a.z - b.z, d3 = a.w - b.w;
    return d0 * d0 + d1 * d1 + d2 * d2 + d3 * d3;
}

__global__ __launch_bounds__(BLOCK) void dcl_main(
    const float* __restrict__ recon_x,
    const float* __restrict__ x,
    const int* __restrict__ assign,
    const float* __restrict__ centers,
    float* __restrict__ out)
{
    const int t   = threadIdx.x;
    const int r   = t >> 4;        // row within 16-row group: 0..15
    const int col = (t & 15) * 4;  // float4 slot within row

    const int fbase = blockIdx.x * 1024 + r * 64 + col;  // float index base
    const int abase = blockIdx.x * 16 + r;               // assignment index base

    float racc = 0.0f, cacc = 0.0f;

    // software-pipelined assignment prefetch (chunk of 4, one chunk ahead)
    int c0 = assign[abase + 0 * ARSTEP];
    int c1 = assign[abase + 1 * ARSTEP];
    int c2 = assign[abase + 2 * ARSTEP];
    int c3 = assign[abase + 3 * ARSTEP];

    #pragma unroll
    for (int k = 0; k < 20; k += 4) {
        const int f0 = fbase + (k + 0) * CHUNK;
        const int f1 = fbase + (k + 1) * CHUNK;
        const int f2 = fbase + (k + 2) * CHUNK;
        const int f3 = fbase + (k + 3) * CHUNK;

        // issue all 12 vector loads before any compute
        const float4 xv0 = *(const float4*)(x + f0);
        const float4 xv1 = *(const float4*)(x + f1);
        const float4 xv2 = *(const float4*)(x + f2);
        const float4 xv3 = *(const float4*)(x + f3);
        const float4 rv0 = *(const float4*)(recon_x + f0);
        const float4 rv1 = *(const float4*)(recon_x + f1);
        const float4 rv2 = *(const float4*)(recon_x + f2);
        const float4 rv3 = *(const float4*)(recon_x + f3);
        const float4 cv0 = *(const float4*)(centers + c0 * DCOLS + col);
        const float4 cv1 = *(const float4*)(centers + c1 * DCOLS + col);
        const float4 cv2 = *(const float4*)(centers + c2 * DCOLS + col);
        const float4 cv3 = *(const float4*)(centers + c3 * DCOLS + col);

        // prefetch next chunk's assignments (wraps to 0 on last iter; harmless)
        const int nk = (k + 4) % 20;
        const int n0 = assign[abase + (nk + 0) * ARSTEP];
        const int n1 = assign[abase + (nk + 1) * ARSTEP];
        const int n2 = assign[abase + (nk + 2) * ARSTEP];
        const int n3 = assign[abase + (nk + 3) * ARSTEP];

        racc += sq4(rv0, xv0) + sq4(rv1, xv1) + sq4(rv2, xv2) + sq4(rv3, xv3);
        cacc += sq4(xv0, cv0) + sq4(xv1, cv1) + sq4(xv2, cv2) + sq4(xv3, cv3);

        c0 = n0; c1 = n1; c2 = n2; c3 = n3;
    }

    // wave-64 butterfly reduce
    #pragma unroll
    for (int off = 32; off > 0; off >>= 1) {
        racc += __shfl_down(racc, off);
        cacc += __shfl_down(cacc, off);
    }

    __shared__ float wsum_r[BLOCK / 64];
    __shared__ float wsum_c[BLOCK / 64];
    const int wave = t >> 6;
    if ((t & 63) == 0) {
        wsum_r[wave] = racc;
        wsum_c[wave] = cacc;
    }
    __syncthreads();

    if (t == 0) {
        float R = 0.0f, C = 0.0f;
        #pragma unroll
        for (int w = 0; w < BLOCK / 64; ++w) { R += wsum_r[w]; C += wsum_c[w]; }
        atomicAdd(&out[1], R);
        atomicAdd(&out[2], C);
        atomicAdd(&out[0], R + C);   // ALPHA=BETA=1
    }
}

extern "C" void kernel_launch(void* const* d_in, const int* in_sizes, int n_in,
                              void* d_out, int out_size, void* d_ws, size_t ws_size,
                              hipStream_t stream) {
    const float* recon_x = (const float*)d_in[0];
    const float* x       = (const float*)d_in[1];
    const int*   assign  = (const int*)d_in[2];
    const float* centers = (const float*)d_in[3];
    float* out = (float*)d_out;

    dcl_zero_out<<<1, 1, 0, stream>>>(out);
    dcl_main<<<GRID, BLOCK, 0, stream>>>(recon_x, x, assign, centers, out);
}